// Round 14
// baseline (1181.092 us; speedup 1.0000x reference)
//
#include <hip/hip_runtime.h>
#include <hip/hip_cooperative_groups.h>
#include <math.h>

namespace cg = cooperative_groups;

#define B_ 8
#define K4 4
#define H_ 256
#define W_ 256
#define HID_ 16
#define DT_ 0.1f
#define STEPS_ 12
#define OMEGA_ 0.9f
#define D_MAX_ 2.0f
#define CHI_MAX_ 2.0f
#define HW_ (H_ * W_)

__device__ __forceinline__ int clampi(int v, int lo, int hi) { return min(max(v, lo), hi); }

__device__ __forceinline__ float softplus_f(float x) {
    return fmaxf(x, 0.0f) + log1pf(expf(-fabsf(x)));
}

// exact replication of reference project_simplex row (K=4)
__device__ __forceinline__ void proj4(float v0, float v1, float v2, float v3,
                                      float& o0, float& o1, float& o2, float& o3) {
    float u0 = v0, u1 = v1, u2 = v2, u3 = v3, t;
    t = fmaxf(u0, u1); u1 = fminf(u0, u1); u0 = t;
    t = fmaxf(u2, u3); u3 = fminf(u2, u3); u2 = t;
    t = fmaxf(u0, u2); u2 = fminf(u0, u2); u0 = t;
    t = fmaxf(u1, u3); u3 = fminf(u1, u3); u1 = t;
    t = fmaxf(u1, u2); u2 = fminf(u1, u2); u1 = t;
    float cs1 = u0 + u1;
    float cs2 = cs1 + u2;
    float c0 = u0 - 1.0f;
    float c1 = cs1 - 1.0f;
    float c2 = cs2 - 1.0f;
    int rho = 0;
    if (u1 - c1 / 2.0f > 0.0f) rho = 1;
    if (u2 - c2 / 3.0f > 0.0f) rho = 2;
    if (u3 - (cs2 + u3 - 1.0f) / 4.0f > 0.0f) rho = 3;
    int ri = rho - 1; if (ri < 0) ri = 0;
    float tau = (ri == 0) ? c0 : (ri == 1) ? (c1 / 2.0f) : (c2 / 3.0f);
    float w0 = fmaxf(v0 - tau, 0.0f);
    float w1 = fmaxf(v1 - tau, 0.0f);
    float w2 = fmaxf(v2 - tau, 0.0f);
    float w3 = fmaxf(v3 - tau, 0.0f);
    float inv = 1.0f / (w0 + w1 + w2 + w3 + 1e-8f);
    o0 = w0 * inv; o1 = w1 * inv; o2 = w2 * inv; o3 = w3 * inv;
}

// ---------------- setup: params + weight transpose ----------------
__global__ void setup_kernel(const float* __restrict__ D_raw,
                             const float* __restrict__ chi_raw,
                             const float* __restrict__ cap_logit,
                             const float* __restrict__ w1,
                             const float* __restrict__ w2,
                             float* __restrict__ params,
                             float* __restrict__ w1t,
                             float* __restrict__ w2t) {
    int tid = threadIdx.x;
    if (tid == 0) {
        for (int c = 0; c < K4; ++c) {
            float d = fminf(softplus_f(D_raw[c]) + 1e-8f, D_MAX_);
            params[c]      = d;
            params[6 + c]  = DT_ * d;
            params[10 + c] = OMEGA_ / (1.0f + DT_ * d * 4.0f);
        }
        params[4] = fminf(softplus_f(chi_raw[0]) + 1e-8f, CHI_MAX_);
        float ct = 1.0f / (1.0f + expf(-cap_logit[0]));
        params[5] = fminf(fmaxf(ct, 0.001f), 0.95f);
    }
    for (int i = tid; i < 576; i += 256) {
        int o = i & 15, rest = i >> 4, ic = rest / 9, k = rest % 9;
        w1t[i] = w1[(o * K4 + ic) * 9 + k];
    }
    for (int i = tid; i < 2304; i += 256) {
        int o = i & 15, rest = i >> 4, ic = rest / 9, k = rest % 9;
        w2t[i] = w2[(o * HID_ + ic) * 9 + k];
    }
}

// ---------------- fused CNN, 16x16 tiles, 512 threads, conv2 oc-split ----
#define PS2_(c,ry,rx) csmem[((c)*20 + (ry))*24 + (rx)]
#define HS2_(o,ry,rx) csmem[1920 + ((o)*18 + (ry))*21 + (rx)]
#define PSUM_ (1920 + 6048)

__global__ __launch_bounds__(512) void cnn_kernel(const float* __restrict__ p0,
                                                  const float* __restrict__ w1t,
                                                  const float* __restrict__ b1,
                                                  const float* __restrict__ w2t,
                                                  const float* __restrict__ b2,
                                                  const float* __restrict__ w3,
                                                  const float* __restrict__ b3,
                                                  float* __restrict__ kmap) {
    __shared__ float csmem[1920 + 6048 + 512];
    const int tid = threadIdx.x;
    const int tx0 = blockIdx.x * 16, ty0 = blockIdx.y * 16, b = blockIdx.z;

    for (int i = tid; i < 4 * 20 * 20; i += 512) {
        int c = i / 400, r = i % 400;
        int ry = r / 20, rx = r % 20;
        int gy = ty0 + ry - 2, gx = tx0 + rx - 2;
        float v = 0.0f;
        if ((unsigned)gy < 256u && (unsigned)gx < 256u)
            v = p0[(((size_t)b * K4 + c) << 16) + gy * W_ + gx];
        PS2_(c, ry, rx) = v;
    }
    __syncthreads();

    if (tid < 18 * 18) {
        int iy = tid / 18, ixx = tid % 18;
        int gy = ty0 + iy - 1, gx = tx0 + ixx - 1;
        bool indom = ((unsigned)gy < 256u) && ((unsigned)gx < 256u);
        float acc[HID_];
#pragma unroll
        for (int o = 0; o < HID_; ++o) acc[o] = b1[o];
        for (int ic = 0; ic < K4; ++ic)
            for (int ky = 0; ky < 3; ++ky)
#pragma unroll
                for (int kx = 0; kx < 3; ++kx) {
                    float v = PS2_(ic, iy + ky, ixx + kx);
                    const float* wp = w1t + (ic * 9 + ky * 3 + kx) * 16;
#pragma unroll
                    for (int o = 0; o < HID_; ++o)
                        acc[o] = fmaf(wp[o], v, acc[o]);
                }
#pragma unroll
        for (int o = 0; o < HID_; ++o)
            HS2_(o, iy, ixx) = indom ? fmaxf(acc[o], 0.0f) : 0.0f;
    }
    __syncthreads();

    {
        int px = tid & 255;
        int hb = __builtin_amdgcn_readfirstlane((tid >> 8) & 1) * 8;
        int iy2 = px >> 4, ix2 = px & 15;
        float acc[8];
#pragma unroll
        for (int o = 0; o < 8; ++o) acc[o] = b2[hb + o];
        for (int ic = 0; ic < HID_; ++ic)
            for (int ky = 0; ky < 3; ++ky)
#pragma unroll
                for (int kx = 0; kx < 3; ++kx) {
                    float v = HS2_(ic, iy2 + ky, ix2 + kx);
                    const float* wp = w2t + (ic * 9 + ky * 3 + kx) * 16 + hb;
#pragma unroll
                    for (int o = 0; o < 8; ++o)
                        acc[o] = fmaf(wp[o], v, acc[o]);
                }
        float s = 0.0f;
#pragma unroll
        for (int o = 0; o < 8; ++o)
            s += w3[hb + o] * fmaxf(acc[o], 0.0f);
        csmem[PSUM_ + (tid >> 8) * 256 + px] = s;
    }
    __syncthreads();

    if (tid < 256) {
        int iy2 = tid >> 4, ix2 = tid & 15;
        float s = b3[0] + csmem[PSUM_ + tid] + csmem[PSUM_ + 256 + tid];
        float km = 1.0f / (1.0f + expf(-s));
        km = fmaxf(km, 1e-6f);
        kmap[((size_t)b << 16) + (ty0 + iy2) * W_ + tx0 + ix2] = km;
    }
}

// ---------------- shared jacobi helpers ----------------
#define JROWS 82
#define JSTR 88
#define JTOT (JROWS * JSTR)

__device__ __forceinline__ float4 jac_core(float4 up, float4 dn, float lf, float rt,
                                           float4 ce, float4 rsv,
                                           bool lm, bool rm, float dtD, float wod) {
    float l0 = lm ? ce.x : lf;
    float r3 = rm ? ce.w : rt;
    float4 ov;
    {
        float lap = up.x + dn.x + l0 + ce.y - 4.0f * ce.x;
        float r = rsv.x - (ce.x - dtD * lap);
        ov.x = ce.x + wod * r;
    }
    {
        float lap = up.y + dn.y + ce.x + ce.z - 4.0f * ce.y;
        float r = rsv.y - (ce.y - dtD * lap);
        ov.y = ce.y + wod * r;
    }
    {
        float lap = up.z + dn.z + ce.y + ce.w - 4.0f * ce.z;
        float r = rsv.z - (ce.z - dtD * lap);
        ov.z = ce.z + wod * r;
    }
    {
        float lap = up.w + dn.w + ce.z + r3 - 4.0f * ce.w;
        float r = rsv.w - (ce.w - dtD * lap);
        ov.w = ce.w + wod * r;
    }
    return ov;
}

// ---------------- cooperative step loop: 256 blocks x 1024 thr (1/CU) --------
// phase P: 8 proj+rhs 16x16 tiles per block (2 halves x 4 LDS groups)
// phase J: 2 bc-units per block (bc = 2*z + half), 64x64 tile, 8 sweeps
__global__ __launch_bounds__(1024, 4) void coop_steps(const float* __restrict__ p0,
                                                      const float* __restrict__ kmap,
                                                      const float* __restrict__ params,
                                                      const int* __restrict__ tumor_idx,
                                                      float* __restrict__ p,
                                                      float* __restrict__ rhs,
                                                      float* __restrict__ xk) {
    cg::grid_group grid = cg::this_grid();
    __shared__ float jsm[2 * JTOT];

    const int tid = threadIdx.x;
    const int lane = tid & 63;
    const int L = (blockIdx.z * 4 + blockIdx.y) * 4 + blockIdx.x;   // 0..255

    // phase-P static mapping
    const int g4 = tid >> 8;            // LDS tile group 0..3
    const int px = tid & 255;
    float* ppg = &jsm[g4 * 1472];       // [4][18][20] per group
#define PPG_(c,ry,rx) ppg[((c)*18 + (ry))*20 + (rx)]

    // phase-J static geometry (same tile for both halves)
    const int jtx0 = blockIdx.x * 64, jty0 = blockIdx.y * 64;
    const int ryA = tid / 20, gA = tid % 20;
    const int gyA = jty0 + ryA - 8;
    const int gx0A = jtx0 + 4 * gA - 8;
    const int ycA = ryA + 1;
    const int yuA = clampi(gyA - 1, 0, 255) - jty0 + 9;
    const int ydA = clampi(gyA + 1, 0, 255) - jty0 + 9;
    const int ixA = 4 + 4 * gA;
    const bool lmA = (gx0A == 0), rmA = (gx0A == 252);
    const bool lfFixA = (lane == 0 && gA > 0);
    const bool rtFixA = (lane == 63 && gA < 19);

    const bool hasB = (tid < 576);      // 576 = 9*64, wave-uniform
    const int itB = tid + 1024;
    const int ryB = itB / 20, gB = itB % 20;
    const int gyB = jty0 + ryB - 8;
    const int gx0B = jtx0 + 4 * gB - 8;
    const int ycB = ryB + 1;
    const int yuB = clampi(gyB - 1, 0, 255) - jty0 + 9;
    const int ydB = clampi(gyB + 1, 0, 255) - jty0 + 9;
    const int ixB = 4 + 4 * gB;
    const bool lmB = (gx0B == 0), rmB = (gx0B == 252);
    const bool lfFixB = (lane == 0 && gB > 0);
    const bool rtFixB = (lane == 63 && gB < 19);

    const float chi = params[4], cap = params[5];
    const int ti = tumor_idx[0];

    for (int s = 0; s < STEPS_; ++s) {
        // ================= phase P: proj(prev xk) + rhs, 8 tiles/block ========
        const float* xin = (s == 0) ? p0 : xk;
        for (int half = 0; half < 2; ++half) {
            int T = L * 8 + half * 4 + g4;   // 0..2047
            int pb = T >> 8;
            int pty0 = ((T >> 4) & 15) * 16;
            int ptx0 = (T & 15) * 16;

            for (int i = px; i < 324; i += 256) {
                int ry = i / 18, rx = i % 18;
                int gy = clampi(pty0 + ry, 0, 255);
                int gx = clampi(ptx0 + rx, 0, 255);
                size_t off = (((size_t)pb * K4) << 16) + gy * W_ + gx;
                float v0 = xin[off], v1 = xin[off + HW_];
                float v2 = xin[off + 2 * HW_], v3 = xin[off + 3 * HW_];
                if (s == 0) {
                    v0 = fmaxf(v0, 0.0f); v1 = fmaxf(v1, 0.0f);
                    v2 = fmaxf(v2, 0.0f); v3 = fmaxf(v3, 0.0f);
                } else {
                    proj4(v0, v1, v2, v3, v0, v1, v2, v3);
                }
                PPG_(0, ry, rx) = v0; PPG_(1, ry, rx) = v1;
                PPG_(2, ry, rx) = v2; PPG_(3, ry, rx) = v3;
            }
            __syncthreads();

            {
                int ry = px >> 4, rx = px & 15;
                int gy = pty0 + ry, gx = ptx0 + rx;
                int row1 = clampi(gy + 1, 0, 255) - pty0;
                int row2 = clampi(gy + 2, 0, 255) - pty0;
                int col1 = clampi(gx + 1, 0, 255) - ptx0;
                int col2 = clampi(gx + 2, 0, 255) - ptx0;
                float pc[4], px1[4], py1[4], g0x[4], g1x[4], g0y[4], g1y[4];
                float s0x = 0.f, s1x = 0.f, s0y = 0.f, s1y = 0.f;
#pragma unroll
                for (int c = 0; c < 4; ++c) {
                    float pcv = PPG_(c, ry, rx);
                    float a   = PPG_(c, ry, col1);
                    float bb  = PPG_(c, ry, col2);
                    float d   = PPG_(c, row1, rx);
                    float e   = PPG_(c, row2, rx);
                    pc[c] = pcv; px1[c] = a; py1[c] = d;
                    g0x[c] = a - pcv;  g1x[c] = bb - a;
                    g0y[c] = d - pcv;  g1y[c] = e - d;
                    s0x += g0x[c]; s1x += g1x[c]; s0y += g0y[c]; s1y += g1y[c];
                }
                float km = kmap[((size_t)pb << 16) + gy * W_ + gx];
                size_t off = (((size_t)pb * K4) << 16) + gy * W_ + gx;
#pragma unroll
                for (int c = 0; c < 4; ++c) {
                    float fx0 = -chi * pc[c]  * (s0x - g0x[c]);
                    float fx1 = -chi * px1[c] * (s1x - g1x[c]);
                    float fy0 = -chi * pc[c]  * (s0y - g0y[c]);
                    float fy1 = -chi * py1[c] * (s1y - g1y[c]);
                    float cross = (fx0 - fx1) + (fy0 - fy1);
                    float react = 0.0f;
                    if (c == ti) {
                        float pt = fminf(fmaxf(pc[c], 0.0f), 1.0f);
                        react = km * pt * (1.0f - pt / cap);
                    }
                    rhs[off + (size_t)c * HW_] = pc[c] + DT_ * (cross + react);
                    p[off + (size_t)c * HW_]   = pc[c];
                }
            }
            __syncthreads();   // PPG reuse across halves
        }
        grid.sync();

        // ================= phase J: 2 bc-units, 8 sweeps each =================
        for (int half = 0; half < 2; ++half) {
            const int bc = blockIdx.z * 2 + half;   // 0..31
            const int jc = bc & 3;
            const float dtD = params[6 + jc];
            const float wod = params[10 + jc];
            const float* pc_ = p + ((size_t)bc << 16);

            for (int i = tid; i < 80 * 80; i += 1024) {
                int r = i / 80, x = i % 80;
                int gy = clampi(jty0 + r - 8, 0, 255);
                int gx = clampi(jtx0 + x - 8, 0, 255);
                jsm[(r + 1) * JSTR + (x + 4)] = pc_[gy * W_ + gx];
            }

            const float* rbase = rhs + ((size_t)bc << 16);
            float4 rsvA, rsvB;
            {
                const float* rr = rbase + clampi(gyA, 0, 255) * W_;
                if (gx0A >= 0 && gx0A <= 252) {
                    rsvA = *(const float4*)&rr[gx0A];
                } else {
                    rsvA.x = rr[clampi(gx0A,     0, 255)];
                    rsvA.y = rr[clampi(gx0A + 1, 0, 255)];
                    rsvA.z = rr[clampi(gx0A + 2, 0, 255)];
                    rsvA.w = rr[clampi(gx0A + 3, 0, 255)];
                }
            }
            if (hasB) {
                const float* rr = rbase + clampi(gyB, 0, 255) * W_;
                if (gx0B >= 0 && gx0B <= 252) {
                    rsvB = *(const float4*)&rr[gx0B];
                } else {
                    rsvB.x = rr[clampi(gx0B,     0, 255)];
                    rsvB.y = rr[clampi(gx0B + 1, 0, 255)];
                    rsvB.z = rr[clampi(gx0B + 2, 0, 255)];
                    rsvB.w = rr[clampi(gx0B + 3, 0, 255)];
                }
            }
            __syncthreads();

            float4 ceA = *(const float4*)&jsm[ycA * JSTR + ixA];
            float4 ceB;
            if (hasB) ceB = *(const float4*)&jsm[ycB * JSTR + ixB];

#pragma unroll
            for (int j = 0; j < 8; ++j) {
                const int rb = j & 1;
                const float* rp = &jsm[rb * JTOT];
                float* wpb = &jsm[(rb ^ 1) * JTOT];

                float lfA = __shfl_up(ceA.w, 1);
                float rtA = __shfl_down(ceA.x, 1);
                if (lfFixA) lfA = rp[ycA * JSTR + ixA - 1];
                if (rtFixA) rtA = rp[ycA * JSTR + ixA + 4];
                float4 upA = *(const float4*)&rp[yuA * JSTR + ixA];
                float4 dnA = *(const float4*)&rp[ydA * JSTR + ixA];
                float4 ovA = jac_core(upA, dnA, lfA, rtA, ceA, rsvA, lmA, rmA, dtD, wod);

                float4 ovB;
                if (hasB) {
                    float lfB = __shfl_up(ceB.w, 1);
                    float rtB = __shfl_down(ceB.x, 1);
                    if (lfFixB) lfB = rp[ycB * JSTR + ixB - 1];
                    if (rtFixB) rtB = rp[ycB * JSTR + ixB + 4];
                    float4 upB = *(const float4*)&rp[yuB * JSTR + ixB];
                    float4 dnB = *(const float4*)&rp[ydB * JSTR + ixB];
                    ovB = jac_core(upB, dnB, lfB, rtB, ceB, rsvB, lmB, rmB, dtD, wod);
                }

                if (j < 7) {
                    *(float4*)&wpb[ycA * JSTR + ixA] = ovA;
                    if (hasB) *(float4*)&wpb[ycB * JSTR + ixB] = ovB;
                    __syncthreads();
                }
                ceA = ovA;
                if (hasB) ceB = ovB;
            }

            if (ryA >= 8 && ryA < 72 && gA >= 2 && gA < 18)
                *(float4*)&xk[((size_t)bc << 16) + gyA * W_ + gx0A] = ceA;
            if (hasB && ryB >= 8 && ryB < 72 && gB >= 2 && gB < 18)
                *(float4*)&xk[((size_t)bc << 16) + gyB * W_ + gx0B] = ceB;
            __syncthreads();   // jsm reuse across halves (buf0 reload)
        }
        grid.sync();
    }

    // ================= final projection (pointwise, in-place on xk) ==========
    for (int k = 0; k < 2; ++k) {
        int i = L * 2048 + k * 1024 + tid;   // 256*2048 = B_*HW_ exactly
        int b = i >> 16, ppx = i & 65535;
        size_t off = (((size_t)b * K4) << 16) + ppx;
        float v0 = xk[off];
        float v1 = xk[off + HW_];
        float v2 = xk[off + 2 * HW_];
        float v3 = xk[off + 3 * HW_];
        proj4(v0, v1, v2, v3, v0, v1, v2, v3);
        xk[off]           = v0;
        xk[off + HW_]     = v1;
        xk[off + 2 * HW_] = v2;
        xk[off + 3 * HW_] = v3;
    }
}

// ---------------- fallback path (R12, proven): proj_rhs + jacobi8 ----------
#define PP_(c,ry,rx) psm[((c)*18 + (ry))*20 + (rx)]

__global__ __launch_bounds__(256) void proj_rhs_kernel(const float* __restrict__ xin,
                                                       const float* __restrict__ kmap,
                                                       const float* __restrict__ params,
                                                       const int* __restrict__ tumor_idx,
                                                       float* __restrict__ pout,
                                                       float* __restrict__ rhs,
                                                       int mode) {
    const int tid = threadIdx.x;
    const int tx0 = blockIdx.x * 16, ty0 = blockIdx.y * 16, b = blockIdx.z;

    if (mode == 2) {
        int ry = tid >> 4, rx = tid & 15;
        size_t off = ((size_t)(b * K4) << 16) + (ty0 + ry) * W_ + tx0 + rx;
        float v0 = xin[off];
        float v1 = xin[off + HW_];
        float v2 = xin[off + 2 * HW_];
        float v3 = xin[off + 3 * HW_];
        proj4(v0, v1, v2, v3, v0, v1, v2, v3);
        pout[off]           = v0;
        pout[off + HW_]     = v1;
        pout[off + 2 * HW_] = v2;
        pout[off + 3 * HW_] = v3;
        return;
    }

    __shared__ float psm[4 * 18 * 20];

    for (int i = tid; i < 18 * 18; i += 256) {
        int ry = i / 18, rx = i % 18;
        int gy = clampi(ty0 + ry, 0, 255);
        int gx = clampi(tx0 + rx, 0, 255);
        size_t off = (((size_t)b * K4) << 16) + gy * W_ + gx;
        float v0 = xin[off], v1 = xin[off + HW_];
        float v2 = xin[off + 2 * HW_], v3 = xin[off + 3 * HW_];
        if (mode == 0) {
            v0 = fmaxf(v0, 0.0f); v1 = fmaxf(v1, 0.0f);
            v2 = fmaxf(v2, 0.0f); v3 = fmaxf(v3, 0.0f);
        } else {
            proj4(v0, v1, v2, v3, v0, v1, v2, v3);
        }
        PP_(0, ry, rx) = v0; PP_(1, ry, rx) = v1;
        PP_(2, ry, rx) = v2; PP_(3, ry, rx) = v3;
    }
    __syncthreads();

    const float chi = params[4], cap = params[5];
    const int ti = tumor_idx[0];
    int ry = tid >> 4, rx = tid & 15;
    int gy = ty0 + ry, gx = tx0 + rx;
    int row1 = clampi(gy + 1, 0, 255) - ty0;
    int row2 = clampi(gy + 2, 0, 255) - ty0;
    int col1 = clampi(gx + 1, 0, 255) - tx0;
    int col2 = clampi(gx + 2, 0, 255) - tx0;
    float pc[4], px1[4], py1[4], g0x[4], g1x[4], g0y[4], g1y[4];
    float s0x = 0.f, s1x = 0.f, s0y = 0.f, s1y = 0.f;
#pragma unroll
    for (int c = 0; c < 4; ++c) {
        float pcv = PP_(c, ry, rx);
        float a   = PP_(c, ry, col1);
        float bb  = PP_(c, ry, col2);
        float d   = PP_(c, row1, rx);
        float e   = PP_(c, row2, rx);
        pc[c] = pcv; px1[c] = a; py1[c] = d;
        g0x[c] = a - pcv;  g1x[c] = bb - a;
        g0y[c] = d - pcv;  g1y[c] = e - d;
        s0x += g0x[c]; s1x += g1x[c]; s0y += g0y[c]; s1y += g1y[c];
    }
    float km = kmap[((size_t)b << 16) + gy * W_ + gx];
    size_t off = (((size_t)b * K4) << 16) + gy * W_ + gx;
#pragma unroll
    for (int c = 0; c < 4; ++c) {
        float fx0 = -chi * pc[c]  * (s0x - g0x[c]);
        float fx1 = -chi * px1[c] * (s1x - g1x[c]);
        float fy0 = -chi * pc[c]  * (s0y - g0y[c]);
        float fy1 = -chi * py1[c] * (s1y - g1y[c]);
        float cross = (fx0 - fx1) + (fy0 - fy1);
        float react = 0.0f;
        if (c == ti) {
            float pt = fminf(fmaxf(pc[c], 0.0f), 1.0f);
            react = km * pt * (1.0f - pt / cap);
        }
        rhs[off + (size_t)c * HW_]  = pc[c] + DT_ * (cross + react);
        pout[off + (size_t)c * HW_] = pc[c];
    }
}

__global__ __launch_bounds__(1024, 8) void jacobi8_kernel(const float* __restrict__ p,
                                                          const float* __restrict__ rhs,
                                                          const float* __restrict__ params,
                                                          float* __restrict__ xk) {
    __shared__ float jsm[2 * JTOT];
    const int tid = threadIdx.x;
    const int lane = tid & 63;
    const int tx0 = blockIdx.x * 64, ty0 = blockIdx.y * 64;
    const int bc = blockIdx.z;
    const int c  = bc & 3;
    const float* pc_ = p + ((size_t)bc << 16);

    for (int i = tid; i < 80 * 80; i += 1024) {
        int r = i / 80, x = i % 80;
        int gy = clampi(ty0 + r - 8, 0, 255);
        int gx = clampi(tx0 + x - 8, 0, 255);
        jsm[(r + 1) * JSTR + (x + 4)] = pc_[gy * W_ + gx];
    }

    const float dtD = params[6 + c];
    const float wod = params[10 + c];
    const float* rbase = rhs + ((size_t)bc << 16);

    const int ryA = tid / 20, gA = tid % 20;
    const int gyA = ty0 + ryA - 8;
    const int gx0A = tx0 + 4 * gA - 8;
    const int ycA = ryA + 1;
    const int yuA = clampi(gyA - 1, 0, 255) - ty0 + 9;
    const int ydA = clampi(gyA + 1, 0, 255) - ty0 + 9;
    const int ixA = 4 + 4 * gA;
    const bool lmA = (gx0A == 0), rmA = (gx0A == 252);
    const bool lfFixA = (lane == 0 && gA > 0);
    const bool rtFixA = (lane == 63 && gA < 19);

    const bool hasB = (tid < 576);
    const int itB = tid + 1024;
    const int ryB = itB / 20, gB = itB % 20;
    const int gyB = ty0 + ryB - 8;
    const int gx0B = tx0 + 4 * gB - 8;
    const int ycB = ryB + 1;
    const int yuB = clampi(gyB - 1, 0, 255) - ty0 + 9;
    const int ydB = clampi(gyB + 1, 0, 255) - ty0 + 9;
    const int ixB = 4 + 4 * gB;
    const bool lmB = (gx0B == 0), rmB = (gx0B == 252);
    const bool lfFixB = (lane == 0 && gB > 0);
    const bool rtFixB = (lane == 63 && gB < 19);

    float4 rsvA, rsvB;
    {
        const float* rr = rbase + clampi(gyA, 0, 255) * W_;
        if (gx0A >= 0 && gx0A <= 252) {
            rsvA = *(const float4*)&rr[gx0A];
        } else {
            rsvA.x = rr[clampi(gx0A,     0, 255)];
            rsvA.y = rr[clampi(gx0A + 1, 0, 255)];
            rsvA.z = rr[clampi(gx0A + 2, 0, 255)];
            rsvA.w = rr[clampi(gx0A + 3, 0, 255)];
        }
    }
    if (hasB) {
        const float* rr = rbase + clampi(gyB, 0, 255) * W_;
        if (gx0B >= 0 && gx0B <= 252) {
            rsvB = *(const float4*)&rr[gx0B];
        } else {
            rsvB.x = rr[clampi(gx0B,     0, 255)];
            rsvB.y = rr[clampi(gx0B + 1, 0, 255)];
            rsvB.z = rr[clampi(gx0B + 2, 0, 255)];
            rsvB.w = rr[clampi(gx0B + 3, 0, 255)];
        }
    }
    __syncthreads();

    float4 ceA = *(const float4*)&jsm[ycA * JSTR + ixA];
    float4 ceB;
    if (hasB) ceB = *(const float4*)&jsm[ycB * JSTR + ixB];

#pragma unroll
    for (int j = 0; j < 8; ++j) {
        const int rb = j & 1;
        const float* rp = &jsm[rb * JTOT];
        float* wpb = &jsm[(rb ^ 1) * JTOT];

        float lfA = __shfl_up(ceA.w, 1);
        float rtA = __shfl_down(ceA.x, 1);
        if (lfFixA) lfA = rp[ycA * JSTR + ixA - 1];
        if (rtFixA) rtA = rp[ycA * JSTR + ixA + 4];
        float4 upA = *(const float4*)&rp[yuA * JSTR + ixA];
        float4 dnA = *(const float4*)&rp[ydA * JSTR + ixA];
        float4 ovA = jac_core(upA, dnA, lfA, rtA, ceA, rsvA, lmA, rmA, dtD, wod);

        float4 ovB;
        if (hasB) {
            float lfB = __shfl_up(ceB.w, 1);
            float rtB = __shfl_down(ceB.x, 1);
            if (lfFixB) lfB = rp[ycB * JSTR + ixB - 1];
            if (rtFixB) rtB = rp[ycB * JSTR + ixB + 4];
            float4 upB = *(const float4*)&rp[yuB * JSTR + ixB];
            float4 dnB = *(const float4*)&rp[ydB * JSTR + ixB];
            ovB = jac_core(upB, dnB, lfB, rtB, ceB, rsvB, lmB, rmB, dtD, wod);
        }

        if (j < 7) {
            *(float4*)&wpb[ycA * JSTR + ixA] = ovA;
            if (hasB) *(float4*)&wpb[ycB * JSTR + ixB] = ovB;
            __syncthreads();
        }
        ceA = ovA;
        if (hasB) ceB = ovB;
    }

    if (ryA >= 8 && ryA < 72 && gA >= 2 && gA < 18)
        *(float4*)&xk[((size_t)bc << 16) + gyA * W_ + gx0A] = ceA;
    if (hasB && ryB >= 8 && ryB < 72 && gB >= 2 && gB < 18)
        *(float4*)&xk[((size_t)bc << 16) + gyB * W_ + gx0B] = ceB;
}

extern "C" void kernel_launch(void* const* d_in, const int* in_sizes, int n_in,
                              void* d_out, int out_size, void* d_ws, size_t ws_size,
                              hipStream_t stream) {
    const float* p0        = (const float*)d_in[0];
    const float* D_raw     = (const float*)d_in[1];
    const float* chi_raw   = (const float*)d_in[2];
    const float* cap_logit = (const float*)d_in[4];
    const float* w1        = (const float*)d_in[5];
    const float* b1        = (const float*)d_in[6];
    const float* w2        = (const float*)d_in[7];
    const float* b2        = (const float*)d_in[8];
    const float* w3        = (const float*)d_in[9];
    const float* b3        = (const float*)d_in[10];
    const int*   tumor_idx = (const int*)d_in[11];

    char* ws = (char*)d_ws;
    float* params = (float*)(ws + 0);
    float* w1t    = (float*)(ws + 1024);
    float* w2t    = (float*)(ws + 4096);
    float* kmap   = (float*)(ws + 65536);                 // 2 MB
    float* p      = (float*)(ws + 4  * 1024 * 1024);      // 8 MB
    float* rhs    = (float*)(ws + 12 * 1024 * 1024);      // 8 MB
    float* xk     = (float*)d_out;                        // d_out doubles as state

    setup_kernel<<<1, 256, 0, stream>>>(D_raw, chi_raw, cap_logit, w1, w2,
                                        params, w1t, w2t);
    dim3 cgrid(16, 16, B_);
    cnn_kernel<<<cgrid, 512, 0, stream>>>(p0, w1t, b1, w2t, b2, w3, b3, kmap);

    void* args[] = {(void*)&p0, (void*)&kmap, (void*)&params, (void*)&tumor_idx,
                    (void*)&p, (void*)&rhs, (void*)&xk};
    hipError_t e = hipLaunchCooperativeKernel((const void*)coop_steps,
                                              dim3(4, 4, 16), dim3(1024),
                                              args, 0, stream);
    if (e != hipSuccess) {
        // fallback: proven R12 split path (bit-identical numerics)
        (void)hipGetLastError();
        dim3 pgrid(16, 16, B_);
        dim3 jgrid(4, 4, B_ * K4);
        for (int s = 0; s < STEPS_; ++s) {
            const float* xin = (s == 0) ? p0 : xk;
            proj_rhs_kernel<<<pgrid, 256, 0, stream>>>(xin, kmap, params, tumor_idx,
                                                       p, rhs, s == 0 ? 0 : 1);
            jacobi8_kernel<<<jgrid, 1024, 0, stream>>>(p, rhs, params, xk);
        }
        proj_rhs_kernel<<<pgrid, 256, 0, stream>>>(xk, kmap, params, tumor_idx,
                                                   xk, rhs, 2);
    }
}

// Round 15
// 357.127 us; speedup vs baseline: 3.3072x; 3.3072x over previous
//
#include <hip/hip_runtime.h>
#include <math.h>

#define B_ 8
#define K4 4
#define H_ 256
#define W_ 256
#define HID_ 16
#define DT_ 0.1f
#define STEPS_ 12
#define OMEGA_ 0.9f
#define D_MAX_ 2.0f
#define CHI_MAX_ 2.0f
#define HW_ (H_ * W_)

__device__ __forceinline__ int clampi(int v, int lo, int hi) { return min(max(v, lo), hi); }

__device__ __forceinline__ float softplus_f(float x) {
    return fmaxf(x, 0.0f) + log1pf(expf(-fabsf(x)));
}

// exact replication of reference project_simplex row (K=4)
__device__ __forceinline__ void proj4(float v0, float v1, float v2, float v3,
                                      float& o0, float& o1, float& o2, float& o3) {
    float u0 = v0, u1 = v1, u2 = v2, u3 = v3, t;
    t = fmaxf(u0, u1); u1 = fminf(u0, u1); u0 = t;
    t = fmaxf(u2, u3); u3 = fminf(u2, u3); u2 = t;
    t = fmaxf(u0, u2); u2 = fminf(u0, u2); u0 = t;
    t = fmaxf(u1, u3); u3 = fminf(u1, u3); u1 = t;
    t = fmaxf(u1, u2); u2 = fminf(u1, u2); u1 = t;
    float cs1 = u0 + u1;
    float cs2 = cs1 + u2;
    float c0 = u0 - 1.0f;
    float c1 = cs1 - 1.0f;
    float c2 = cs2 - 1.0f;
    int rho = 0;
    if (u1 - c1 / 2.0f > 0.0f) rho = 1;
    if (u2 - c2 / 3.0f > 0.0f) rho = 2;
    if (u3 - (cs2 + u3 - 1.0f) / 4.0f > 0.0f) rho = 3;
    int ri = rho - 1; if (ri < 0) ri = 0;
    float tau = (ri == 0) ? c0 : (ri == 1) ? (c1 / 2.0f) : (c2 / 3.0f);
    float w0 = fmaxf(v0 - tau, 0.0f);
    float w1 = fmaxf(v1 - tau, 0.0f);
    float w2 = fmaxf(v2 - tau, 0.0f);
    float w3 = fmaxf(v3 - tau, 0.0f);
    float inv = 1.0f / (w0 + w1 + w2 + w3 + 1e-8f);
    o0 = w0 * inv; o1 = w1 * inv; o2 = w2 * inv; o3 = w3 * inv;
}

// ---------------- setup: params + weight transpose ----------------
__global__ void setup_kernel(const float* __restrict__ D_raw,
                             const float* __restrict__ chi_raw,
                             const float* __restrict__ cap_logit,
                             const float* __restrict__ w1,
                             const float* __restrict__ w2,
                             float* __restrict__ params,
                             float* __restrict__ w1t,
                             float* __restrict__ w2t) {
    int tid = threadIdx.x;
    if (tid == 0) {
        for (int c = 0; c < K4; ++c) {
            float d = fminf(softplus_f(D_raw[c]) + 1e-8f, D_MAX_);
            params[c]      = d;
            params[6 + c]  = DT_ * d;
            params[10 + c] = OMEGA_ / (1.0f + DT_ * d * 4.0f);
        }
        params[4] = fminf(softplus_f(chi_raw[0]) + 1e-8f, CHI_MAX_);
        float ct = 1.0f / (1.0f + expf(-cap_logit[0]));
        params[5] = fminf(fmaxf(ct, 0.001f), 0.95f);
    }
    for (int i = tid; i < 576; i += 256) {
        int o = i & 15, rest = i >> 4, ic = rest / 9, k = rest % 9;
        w1t[i] = w1[(o * K4 + ic) * 9 + k];
    }
    for (int i = tid; i < 2304; i += 256) {
        int o = i & 15, rest = i >> 4, ic = rest / 9, k = rest % 9;
        w2t[i] = w2[(o * HID_ + ic) * 9 + k];
    }
}

// ---------------- fused CNN, 16x16 tiles, 512 threads, vectorized LDS ----
// PS [20][20][4] (ch-interleaved) = 1600, HS [18][18][20] (16 oc + pad) = 6480,
// psum [2][256] = 512. All stencil taps are ds_read_b128, conflict-free.
#define HSBASE 1600
#define PSUMW  (1600 + 6480)

__global__ __launch_bounds__(512) void cnn_kernel(const float* __restrict__ p0,
                                                  const float* __restrict__ w1t,
                                                  const float* __restrict__ b1,
                                                  const float* __restrict__ w2t,
                                                  const float* __restrict__ b2,
                                                  const float* __restrict__ w3,
                                                  const float* __restrict__ b3,
                                                  float* __restrict__ kmap) {
    __shared__ float csmem[1600 + 6480 + 512];
    const int tid = threadIdx.x;
    const int tx0 = blockIdx.x * 16, ty0 = blockIdx.y * 16, b = blockIdx.z;

    // load p0 tile halo-2, zero-pad, channel-interleaved
    if (tid < 400) {
        int ry = tid / 20, rx = tid % 20;
        int gy = ty0 + ry - 2, gx = tx0 + rx - 2;
        float4 v = make_float4(0.f, 0.f, 0.f, 0.f);
        if ((unsigned)gy < 256u && (unsigned)gx < 256u) {
            size_t off = (((size_t)b * K4) << 16) + gy * W_ + gx;
            v.x = p0[off];
            v.y = p0[off + HW_];
            v.z = p0[off + 2 * HW_];
            v.w = p0[off + 3 * HW_];
        }
        *(float4*)&csmem[(ry * 20 + rx) * 4] = v;
    }
    __syncthreads();

    // conv1: 18x18 items, 9 b128 taps, 16 oc each
    if (tid < 18 * 18) {
        int iy = tid / 18, ixx = tid % 18;
        int gy = ty0 + iy - 1, gx = tx0 + ixx - 1;
        bool indom = ((unsigned)gy < 256u) && ((unsigned)gx < 256u);
        float acc[HID_];
#pragma unroll
        for (int o = 0; o < HID_; ++o) acc[o] = b1[o];
        for (int ky = 0; ky < 3; ++ky)
#pragma unroll
            for (int kx = 0; kx < 3; ++kx) {
                float4 v = *(const float4*)&csmem[((iy + ky) * 20 + (ixx + kx)) * 4];
                int k = ky * 3 + kx;
                const float* wp0 = w1t + (0 * 9 + k) * 16;
                const float* wp1 = w1t + (1 * 9 + k) * 16;
                const float* wp2 = w1t + (2 * 9 + k) * 16;
                const float* wp3 = w1t + (3 * 9 + k) * 16;
#pragma unroll
                for (int o = 0; o < HID_; ++o) {
                    float a = fmaf(wp0[o], v.x, acc[o]);
                    a = fmaf(wp1[o], v.y, a);
                    a = fmaf(wp2[o], v.z, a);
                    acc[o] = fmaf(wp3[o], v.w, a);
                }
            }
        float* hp = &csmem[HSBASE + (iy * 18 + ixx) * 20];
#pragma unroll
        for (int o = 0; o < HID_; ++o)
            hp[o] = indom ? fmaxf(acc[o], 0.0f) : 0.0f;
    }
    __syncthreads();

    // conv2 + relu + partial 1x1: 2 threads per px, 8 oc each; 4 b128 per tap
    {
        int px = tid & 255;
        int hb = __builtin_amdgcn_readfirstlane((tid >> 8) & 1) * 8;
        int iy2 = px >> 4, ix2 = px & 15;
        float acc[8];
#pragma unroll
        for (int o = 0; o < 8; ++o) acc[o] = b2[hb + o];
        for (int ky = 0; ky < 3; ++ky)
#pragma unroll
            for (int kx = 0; kx < 3; ++kx) {
                const float* hp = &csmem[HSBASE + ((iy2 + ky) * 18 + (ix2 + kx)) * 20];
                float4 va = *(const float4*)&hp[0];
                float4 vb = *(const float4*)&hp[4];
                float4 vc = *(const float4*)&hp[8];
                float4 vd = *(const float4*)&hp[12];
                float v[16] = {va.x, va.y, va.z, va.w, vb.x, vb.y, vb.z, vb.w,
                               vc.x, vc.y, vc.z, vc.w, vd.x, vd.y, vd.z, vd.w};
                int t = ky * 3 + kx;
#pragma unroll
                for (int ic = 0; ic < HID_; ++ic) {
                    const float* wp = w2t + (ic * 9 + t) * 16 + hb;
#pragma unroll
                    for (int o = 0; o < 8; ++o)
                        acc[o] = fmaf(wp[o], v[ic], acc[o]);
                }
            }
        float s = 0.0f;
#pragma unroll
        for (int o = 0; o < 8; ++o)
            s += w3[hb + o] * fmaxf(acc[o], 0.0f);
        csmem[PSUMW + (tid >> 8) * 256 + px] = s;
    }
    __syncthreads();

    if (tid < 256) {
        int iy2 = tid >> 4, ix2 = tid & 15;
        float s = b3[0] + csmem[PSUMW + tid] + csmem[PSUMW + 256 + tid];
        float km = 1.0f / (1.0f + expf(-s));
        km = fmaxf(km, 1e-6f);
        kmap[((size_t)b << 16) + (ty0 + iy2) * W_ + tx0 + ix2] = km;
    }
}

// ---------------- proj_rhs: projection (prev step) + rhs (this step) ----------
#define PP_(c,ry,rx) psm[((c)*18 + (ry))*20 + (rx)]

__global__ __launch_bounds__(256) void proj_rhs_kernel(const float* __restrict__ xin,
                                                       const float* __restrict__ kmap,
                                                       const float* __restrict__ params,
                                                       const int* __restrict__ tumor_idx,
                                                       float* __restrict__ pout,
                                                       float* __restrict__ rhs,
                                                       int mode) {
    const int tid = threadIdx.x;
    const int tx0 = blockIdx.x * 16, ty0 = blockIdx.y * 16, b = blockIdx.z;

    if (mode == 2) {   // final projection, in-place pointwise
        int ry = tid >> 4, rx = tid & 15;
        size_t off = ((size_t)(b * K4) << 16) + (ty0 + ry) * W_ + tx0 + rx;
        float v0 = xin[off];
        float v1 = xin[off + HW_];
        float v2 = xin[off + 2 * HW_];
        float v3 = xin[off + 3 * HW_];
        proj4(v0, v1, v2, v3, v0, v1, v2, v3);
        pout[off]           = v0;
        pout[off + HW_]     = v1;
        pout[off + 2 * HW_] = v2;
        pout[off + 3 * HW_] = v3;
        return;
    }

    __shared__ float psm[4 * 18 * 20];

    // build PP on rel [0..17]^2 (clamped reads give edge-replicate)
    for (int i = tid; i < 18 * 18; i += 256) {
        int ry = i / 18, rx = i % 18;
        int gy = clampi(ty0 + ry, 0, 255);
        int gx = clampi(tx0 + rx, 0, 255);
        size_t off = (((size_t)b * K4) << 16) + gy * W_ + gx;
        float v0 = xin[off], v1 = xin[off + HW_];
        float v2 = xin[off + 2 * HW_], v3 = xin[off + 3 * HW_];
        if (mode == 0) {
            v0 = fmaxf(v0, 0.0f); v1 = fmaxf(v1, 0.0f);
            v2 = fmaxf(v2, 0.0f); v3 = fmaxf(v3, 0.0f);
        } else {
            proj4(v0, v1, v2, v3, v0, v1, v2, v3);
        }
        PP_(0, ry, rx) = v0; PP_(1, ry, rx) = v1;
        PP_(2, ry, rx) = v2; PP_(3, ry, rx) = v3;
    }
    __syncthreads();

    // rhs on 16x16, 1 px/thread (reference arithmetic order); also write p
    const float chi = params[4], cap = params[5];
    const int ti = tumor_idx[0];
    int ry = tid >> 4, rx = tid & 15;
    int gy = ty0 + ry, gx = tx0 + rx;
    int row1 = clampi(gy + 1, 0, 255) - ty0;
    int row2 = clampi(gy + 2, 0, 255) - ty0;
    int col1 = clampi(gx + 1, 0, 255) - tx0;
    int col2 = clampi(gx + 2, 0, 255) - tx0;
    float pc[4], px1[4], py1[4], g0x[4], g1x[4], g0y[4], g1y[4];
    float s0x = 0.f, s1x = 0.f, s0y = 0.f, s1y = 0.f;
#pragma unroll
    for (int c = 0; c < 4; ++c) {
        float pcv = PP_(c, ry, rx);
        float a   = PP_(c, ry, col1);
        float bb  = PP_(c, ry, col2);
        float d   = PP_(c, row1, rx);
        float e   = PP_(c, row2, rx);
        pc[c] = pcv; px1[c] = a; py1[c] = d;
        g0x[c] = a - pcv;  g1x[c] = bb - a;
        g0y[c] = d - pcv;  g1y[c] = e - d;
        s0x += g0x[c]; s1x += g1x[c]; s0y += g0y[c]; s1y += g1y[c];
    }
    float km = kmap[((size_t)b << 16) + gy * W_ + gx];
    size_t off = (((size_t)b * K4) << 16) + gy * W_ + gx;
#pragma unroll
    for (int c = 0; c < 4; ++c) {
        float fx0 = -chi * pc[c]  * (s0x - g0x[c]);
        float fx1 = -chi * px1[c] * (s1x - g1x[c]);
        float fy0 = -chi * pc[c]  * (s0y - g0y[c]);
        float fy1 = -chi * py1[c] * (s1y - g1y[c]);
        float cross = (fx0 - fx1) + (fy0 - fy1);
        float react = 0.0f;
        if (c == ti) {
            float pt = fminf(fmaxf(pc[c], 0.0f), 1.0f);
            react = km * pt * (1.0f - pt / cap);
        }
        rhs[off + (size_t)c * HW_]  = pc[c] + DT_ * (cross + react);
        pout[off + (size_t)c * HW_] = pc[c];
    }
}

// ---------------- jacobi8: per-channel, 64x64 tile, 8 sweeps in LDS ----------
#define JROWS 82
#define JSTR 88
#define JTOT (JROWS * JSTR)

__device__ __forceinline__ float4 jac_core(float4 up, float4 dn, float lf, float rt,
                                           float4 ce, float4 rsv,
                                           bool lm, bool rm, float dtD, float wod) {
    float l0 = lm ? ce.x : lf;
    float r3 = rm ? ce.w : rt;
    float4 ov;
    {
        float lap = up.x + dn.x + l0 + ce.y - 4.0f * ce.x;
        float r = rsv.x - (ce.x - dtD * lap);
        ov.x = ce.x + wod * r;
    }
    {
        float lap = up.y + dn.y + ce.x + ce.z - 4.0f * ce.y;
        float r = rsv.y - (ce.y - dtD * lap);
        ov.y = ce.y + wod * r;
    }
    {
        float lap = up.z + dn.z + ce.y + ce.w - 4.0f * ce.z;
        float r = rsv.z - (ce.z - dtD * lap);
        ov.z = ce.z + wod * r;
    }
    {
        float lap = up.w + dn.w + ce.z + r3 - 4.0f * ce.w;
        float r = rsv.w - (ce.w - dtD * lap);
        ov.w = ce.w + wod * r;
    }
    return ov;
}

__global__ __launch_bounds__(1024, 8) void jacobi8_kernel(const float* __restrict__ p,
                                                          const float* __restrict__ rhs,
                                                          const float* __restrict__ params,
                                                          float* __restrict__ xk) {
    __shared__ float jsm[2 * JTOT];
    const int tid = threadIdx.x;
    const int lane = tid & 63;
    const int tx0 = blockIdx.x * 64, ty0 = blockIdx.y * 64;
    const int bc = blockIdx.z;                 // b*4 + c
    const int c  = bc & 3;
    const float* pc_ = p + ((size_t)bc << 16);

    // load region rel [-8..71]^2 (edge-replicate clamp)
    for (int i = tid; i < 80 * 80; i += 1024) {
        int r = i / 80, x = i % 80;
        int gy = clampi(ty0 + r - 8, 0, 255);
        int gx = clampi(tx0 + x - 8, 0, 255);
        jsm[(r + 1) * JSTR + (x + 4)] = pc_[gy * W_ + gx];
    }

    const float dtD = params[6 + c];
    const float wod = params[10 + c];
    const float* rbase = rhs + ((size_t)bc << 16);

    const int ryA = tid / 20, gA = tid % 20;
    const int gyA = ty0 + ryA - 8;
    const int gx0A = tx0 + 4 * gA - 8;
    const int ycA = ryA + 1;
    const int yuA = clampi(gyA - 1, 0, 255) - ty0 + 9;
    const int ydA = clampi(gyA + 1, 0, 255) - ty0 + 9;
    const int ixA = 4 + 4 * gA;
    const bool lmA = (gx0A == 0), rmA = (gx0A == 252);
    const bool lfFixA = (lane == 0 && gA > 0);
    const bool rtFixA = (lane == 63 && gA < 19);

    const bool hasB = (tid < 576);
    const int itB = tid + 1024;
    const int ryB = itB / 20, gB = itB % 20;
    const int gyB = ty0 + ryB - 8;
    const int gx0B = tx0 + 4 * gB - 8;
    const int ycB = ryB + 1;
    const int yuB = clampi(gyB - 1, 0, 255) - ty0 + 9;
    const int ydB = clampi(gyB + 1, 0, 255) - ty0 + 9;
    const int ixB = 4 + 4 * gB;
    const bool lmB = (gx0B == 0), rmB = (gx0B == 252);
    const bool lfFixB = (lane == 0 && gB > 0);
    const bool rtFixB = (lane == 63 && gB < 19);

    float4 rsvA, rsvB;
    {
        const float* rr = rbase + clampi(gyA, 0, 255) * W_;
        if (gx0A >= 0 && gx0A <= 252) {
            rsvA = *(const float4*)&rr[gx0A];
        } else {
            rsvA.x = rr[clampi(gx0A,     0, 255)];
            rsvA.y = rr[clampi(gx0A + 1, 0, 255)];
            rsvA.z = rr[clampi(gx0A + 2, 0, 255)];
            rsvA.w = rr[clampi(gx0A + 3, 0, 255)];
        }
    }
    if (hasB) {
        const float* rr = rbase + clampi(gyB, 0, 255) * W_;
        if (gx0B >= 0 && gx0B <= 252) {
            rsvB = *(const float4*)&rr[gx0B];
        } else {
            rsvB.x = rr[clampi(gx0B,     0, 255)];
            rsvB.y = rr[clampi(gx0B + 1, 0, 255)];
            rsvB.z = rr[clampi(gx0B + 2, 0, 255)];
            rsvB.w = rr[clampi(gx0B + 3, 0, 255)];
        }
    }
    __syncthreads();

    float4 ceA = *(const float4*)&jsm[ycA * JSTR + ixA];
    float4 ceB;
    if (hasB) ceB = *(const float4*)&jsm[ycB * JSTR + ixB];

#pragma unroll
    for (int j = 0; j < 8; ++j) {
        const int rb = j & 1;
        const float* rp = &jsm[rb * JTOT];
        float* wpb = &jsm[(rb ^ 1) * JTOT];

        float lfA = __shfl_up(ceA.w, 1);
        float rtA = __shfl_down(ceA.x, 1);
        if (lfFixA) lfA = rp[ycA * JSTR + ixA - 1];
        if (rtFixA) rtA = rp[ycA * JSTR + ixA + 4];
        float4 upA = *(const float4*)&rp[yuA * JSTR + ixA];
        float4 dnA = *(const float4*)&rp[ydA * JSTR + ixA];
        float4 ovA = jac_core(upA, dnA, lfA, rtA, ceA, rsvA, lmA, rmA, dtD, wod);

        float4 ovB;
        if (hasB) {
            float lfB = __shfl_up(ceB.w, 1);
            float rtB = __shfl_down(ceB.x, 1);
            if (lfFixB) lfB = rp[ycB * JSTR + ixB - 1];
            if (rtFixB) rtB = rp[ycB * JSTR + ixB + 4];
            float4 upB = *(const float4*)&rp[yuB * JSTR + ixB];
            float4 dnB = *(const float4*)&rp[ydB * JSTR + ixB];
            ovB = jac_core(upB, dnB, lfB, rtB, ceB, rsvB, lmB, rmB, dtD, wod);
        }

        if (j < 7) {
            *(float4*)&wpb[ycA * JSTR + ixA] = ovA;
            if (hasB) *(float4*)&wpb[ycB * JSTR + ixB] = ovB;
            __syncthreads();
        }
        ceA = ovA;
        if (hasB) ceB = ovB;
    }

    if (ryA >= 8 && ryA < 72 && gA >= 2 && gA < 18)
        *(float4*)&xk[((size_t)bc << 16) + gyA * W_ + gx0A] = ceA;
    if (hasB && ryB >= 8 && ryB < 72 && gB >= 2 && gB < 18)
        *(float4*)&xk[((size_t)bc << 16) + gyB * W_ + gx0B] = ceB;
}

extern "C" void kernel_launch(void* const* d_in, const int* in_sizes, int n_in,
                              void* d_out, int out_size, void* d_ws, size_t ws_size,
                              hipStream_t stream) {
    const float* p0        = (const float*)d_in[0];
    const float* D_raw     = (const float*)d_in[1];
    const float* chi_raw   = (const float*)d_in[2];
    const float* cap_logit = (const float*)d_in[4];
    const float* w1        = (const float*)d_in[5];
    const float* b1        = (const float*)d_in[6];
    const float* w2        = (const float*)d_in[7];
    const float* b2        = (const float*)d_in[8];
    const float* w3        = (const float*)d_in[9];
    const float* b3        = (const float*)d_in[10];
    const int*   tumor_idx = (const int*)d_in[11];

    char* ws = (char*)d_ws;
    float* params = (float*)(ws + 0);
    float* w1t    = (float*)(ws + 1024);
    float* w2t    = (float*)(ws + 4096);
    float* kmap   = (float*)(ws + 65536);                 // 2 MB
    float* p      = (float*)(ws + 4  * 1024 * 1024);      // 8 MB
    float* rhs    = (float*)(ws + 12 * 1024 * 1024);      // 8 MB
    float* xk     = (float*)d_out;                        // d_out doubles as xk scratch

    setup_kernel<<<1, 256, 0, stream>>>(D_raw, chi_raw, cap_logit, w1, w2,
                                        params, w1t, w2t);
    dim3 cgrid(16, 16, B_);
    cnn_kernel<<<cgrid, 512, 0, stream>>>(p0, w1t, b1, w2t, b2, w3, b3, kmap);

    dim3 pgrid(16, 16, B_);
    dim3 jgrid(4, 4, B_ * K4);
    for (int s = 0; s < STEPS_; ++s) {
        const float* xin = (s == 0) ? p0 : xk;
        proj_rhs_kernel<<<pgrid, 256, 0, stream>>>(xin, kmap, params, tumor_idx,
                                                   p, rhs, s == 0 ? 0 : 1);
        jacobi8_kernel<<<jgrid, 1024, 0, stream>>>(p, rhs, params, xk);
    }
    // final projection, in-place on d_out
    proj_rhs_kernel<<<pgrid, 256, 0, stream>>>(xk, kmap, params, tumor_idx,
                                               xk, rhs, 2);
}

// Round 16
// 355.350 us; speedup vs baseline: 3.3237x; 1.0050x over previous
//
#include <hip/hip_runtime.h>
#include <math.h>

#define B_ 8
#define K4 4
#define H_ 256
#define W_ 256
#define HID_ 16
#define DT_ 0.1f
#define STEPS_ 12
#define OMEGA_ 0.9f
#define D_MAX_ 2.0f
#define CHI_MAX_ 2.0f
#define HW_ (H_ * W_)

__device__ __forceinline__ int clampi(int v, int lo, int hi) { return min(max(v, lo), hi); }

__device__ __forceinline__ float softplus_f(float x) {
    return fmaxf(x, 0.0f) + log1pf(expf(-fabsf(x)));
}

// exact replication of reference project_simplex row (K=4)
__device__ __forceinline__ void proj4(float v0, float v1, float v2, float v3,
                                      float& o0, float& o1, float& o2, float& o3) {
    float u0 = v0, u1 = v1, u2 = v2, u3 = v3, t;
    t = fmaxf(u0, u1); u1 = fminf(u0, u1); u0 = t;
    t = fmaxf(u2, u3); u3 = fminf(u2, u3); u2 = t;
    t = fmaxf(u0, u2); u2 = fminf(u0, u2); u0 = t;
    t = fmaxf(u1, u3); u3 = fminf(u1, u3); u1 = t;
    t = fmaxf(u1, u2); u2 = fminf(u1, u2); u1 = t;
    float cs1 = u0 + u1;
    float cs2 = cs1 + u2;
    float c0 = u0 - 1.0f;
    float c1 = cs1 - 1.0f;
    float c2 = cs2 - 1.0f;
    int rho = 0;
    if (u1 - c1 / 2.0f > 0.0f) rho = 1;
    if (u2 - c2 / 3.0f > 0.0f) rho = 2;
    if (u3 - (cs2 + u3 - 1.0f) / 4.0f > 0.0f) rho = 3;
    int ri = rho - 1; if (ri < 0) ri = 0;
    float tau = (ri == 0) ? c0 : (ri == 1) ? (c1 / 2.0f) : (c2 / 3.0f);
    float w0 = fmaxf(v0 - tau, 0.0f);
    float w1 = fmaxf(v1 - tau, 0.0f);
    float w2 = fmaxf(v2 - tau, 0.0f);
    float w3 = fmaxf(v3 - tau, 0.0f);
    float inv = 1.0f / (w0 + w1 + w2 + w3 + 1e-8f);
    o0 = w0 * inv; o1 = w1 * inv; o2 = w2 * inv; o3 = w3 * inv;
}

// ---------------- setup: params + weight transpose ----------------
__global__ void setup_kernel(const float* __restrict__ D_raw,
                             const float* __restrict__ chi_raw,
                             const float* __restrict__ cap_logit,
                             const float* __restrict__ w1,
                             const float* __restrict__ w2,
                             float* __restrict__ params,
                             float* __restrict__ w1t,
                             float* __restrict__ w2t) {
    int tid = threadIdx.x;
    if (tid == 0) {
        for (int c = 0; c < K4; ++c) {
            float d = fminf(softplus_f(D_raw[c]) + 1e-8f, D_MAX_);
            params[c]      = d;
            params[6 + c]  = DT_ * d;
            params[10 + c] = OMEGA_ / (1.0f + DT_ * d * 4.0f);
        }
        params[4] = fminf(softplus_f(chi_raw[0]) + 1e-8f, CHI_MAX_);
        float ct = 1.0f / (1.0f + expf(-cap_logit[0]));
        params[5] = fminf(fmaxf(ct, 0.001f), 0.95f);
    }
    for (int i = tid; i < 576; i += 256) {
        int o = i & 15, rest = i >> 4, ic = rest / 9, k = rest % 9;
        w1t[i] = w1[(o * K4 + ic) * 9 + k];
    }
    for (int i = tid; i < 2304; i += 256) {
        int o = i & 15, rest = i >> 4, ic = rest / 9, k = rest % 9;
        w2t[i] = w2[(o * HID_ + ic) * 9 + k];
    }
}

// ---------------- fused CNN, 16x16 tiles, 512 threads, vectorized LDS ----
// PS [20][20][4] (ch-interleaved) = 1600, HS [18][18][20] (16 oc + pad) = 6480,
// psum [2][256] = 512. All stencil taps AND HS writes are ds_*_b128.
#define HSBASE 1600
#define PSUMW  (1600 + 6480)

__global__ __launch_bounds__(512) void cnn_kernel(const float* __restrict__ p0,
                                                  const float* __restrict__ w1t,
                                                  const float* __restrict__ b1,
                                                  const float* __restrict__ w2t,
                                                  const float* __restrict__ b2,
                                                  const float* __restrict__ w3,
                                                  const float* __restrict__ b3,
                                                  float* __restrict__ kmap) {
    __shared__ float csmem[1600 + 6480 + 512];
    const int tid = threadIdx.x;
    const int tx0 = blockIdx.x * 16, ty0 = blockIdx.y * 16, b = blockIdx.z;

    // load p0 tile halo-2, zero-pad, channel-interleaved
    if (tid < 400) {
        int ry = tid / 20, rx = tid % 20;
        int gy = ty0 + ry - 2, gx = tx0 + rx - 2;
        float4 v = make_float4(0.f, 0.f, 0.f, 0.f);
        if ((unsigned)gy < 256u && (unsigned)gx < 256u) {
            size_t off = (((size_t)b * K4) << 16) + gy * W_ + gx;
            v.x = p0[off];
            v.y = p0[off + HW_];
            v.z = p0[off + 2 * HW_];
            v.w = p0[off + 3 * HW_];
        }
        *(float4*)&csmem[(ry * 20 + rx) * 4] = v;
    }
    __syncthreads();

    // conv1: 18x18 items, 9 b128 taps, 16 oc each; b128 HS writes
    if (tid < 18 * 18) {
        int iy = tid / 18, ixx = tid % 18;
        int gy = ty0 + iy - 1, gx = tx0 + ixx - 1;
        bool indom = ((unsigned)gy < 256u) && ((unsigned)gx < 256u);
        float acc[HID_];
#pragma unroll
        for (int o = 0; o < HID_; ++o) acc[o] = b1[o];
        for (int ky = 0; ky < 3; ++ky)
#pragma unroll
            for (int kx = 0; kx < 3; ++kx) {
                float4 v = *(const float4*)&csmem[((iy + ky) * 20 + (ixx + kx)) * 4];
                int k = ky * 3 + kx;
                const float* wp0 = w1t + (0 * 9 + k) * 16;
                const float* wp1 = w1t + (1 * 9 + k) * 16;
                const float* wp2 = w1t + (2 * 9 + k) * 16;
                const float* wp3 = w1t + (3 * 9 + k) * 16;
#pragma unroll
                for (int o = 0; o < HID_; ++o) {
                    float a = fmaf(wp0[o], v.x, acc[o]);
                    a = fmaf(wp1[o], v.y, a);
                    a = fmaf(wp2[o], v.z, a);
                    acc[o] = fmaf(wp3[o], v.w, a);
                }
            }
        float* hp = &csmem[HSBASE + (iy * 18 + ixx) * 20];
#pragma unroll
        for (int o4 = 0; o4 < 4; ++o4) {
            float4 hv;
            hv.x = indom ? fmaxf(acc[4 * o4 + 0], 0.0f) : 0.0f;
            hv.y = indom ? fmaxf(acc[4 * o4 + 1], 0.0f) : 0.0f;
            hv.z = indom ? fmaxf(acc[4 * o4 + 2], 0.0f) : 0.0f;
            hv.w = indom ? fmaxf(acc[4 * o4 + 3], 0.0f) : 0.0f;
            *(float4*)&hp[4 * o4] = hv;
        }
    }
    __syncthreads();

    // conv2 + relu + partial 1x1: 2 threads per px, 8 oc each; 4 b128 per tap
    {
        int px = tid & 255;
        int hb = __builtin_amdgcn_readfirstlane((tid >> 8) & 1) * 8;
        int iy2 = px >> 4, ix2 = px & 15;
        float acc[8];
#pragma unroll
        for (int o = 0; o < 8; ++o) acc[o] = b2[hb + o];
        for (int ky = 0; ky < 3; ++ky)
#pragma unroll
            for (int kx = 0; kx < 3; ++kx) {
                const float* hp = &csmem[HSBASE + ((iy2 + ky) * 18 + (ix2 + kx)) * 20];
                float4 va = *(const float4*)&hp[0];
                float4 vb = *(const float4*)&hp[4];
                float4 vc = *(const float4*)&hp[8];
                float4 vd = *(const float4*)&hp[12];
                float v[16] = {va.x, va.y, va.z, va.w, vb.x, vb.y, vb.z, vb.w,
                               vc.x, vc.y, vc.z, vc.w, vd.x, vd.y, vd.z, vd.w};
                int t = ky * 3 + kx;
#pragma unroll
                for (int ic = 0; ic < HID_; ++ic) {
                    const float* wp = w2t + (ic * 9 + t) * 16 + hb;
#pragma unroll
                    for (int o = 0; o < 8; ++o)
                        acc[o] = fmaf(wp[o], v[ic], acc[o]);
                }
            }
        float s = 0.0f;
#pragma unroll
        for (int o = 0; o < 8; ++o)
            s += w3[hb + o] * fmaxf(acc[o], 0.0f);
        csmem[PSUMW + (tid >> 8) * 256 + px] = s;
    }
    __syncthreads();

    if (tid < 256) {
        int iy2 = tid >> 4, ix2 = tid & 15;
        float s = b3[0] + csmem[PSUMW + tid] + csmem[PSUMW + 256 + tid];
        float km = 1.0f / (1.0f + expf(-s));
        km = fmaxf(km, 1e-6f);
        kmap[((size_t)b << 16) + (ty0 + iy2) * W_ + tx0 + ix2] = km;
    }
}

// ---------------- proj_rhs: projection (prev step) + rhs (this step) ----------
#define PP_(c,ry,rx) psm[((c)*18 + (ry))*20 + (rx)]

__global__ __launch_bounds__(256) void proj_rhs_kernel(const float* __restrict__ xin,
                                                       const float* __restrict__ kmap,
                                                       const float* __restrict__ params,
                                                       const int* __restrict__ tumor_idx,
                                                       float* __restrict__ pout,
                                                       float* __restrict__ rhs,
                                                       int mode) {
    const int tid = threadIdx.x;
    const int tx0 = blockIdx.x * 16, ty0 = blockIdx.y * 16, b = blockIdx.z;

    if (mode == 2) {   // final projection, in-place pointwise
        int ry = tid >> 4, rx = tid & 15;
        size_t off = ((size_t)(b * K4) << 16) + (ty0 + ry) * W_ + tx0 + rx;
        float v0 = xin[off];
        float v1 = xin[off + HW_];
        float v2 = xin[off + 2 * HW_];
        float v3 = xin[off + 3 * HW_];
        proj4(v0, v1, v2, v3, v0, v1, v2, v3);
        pout[off]           = v0;
        pout[off + HW_]     = v1;
        pout[off + 2 * HW_] = v2;
        pout[off + 3 * HW_] = v3;
        return;
    }

    __shared__ float psm[4 * 18 * 20];

    // build PP on rel [0..17]^2 (clamped reads give edge-replicate)
    for (int i = tid; i < 18 * 18; i += 256) {
        int ry = i / 18, rx = i % 18;
        int gy = clampi(ty0 + ry, 0, 255);
        int gx = clampi(tx0 + rx, 0, 255);
        size_t off = (((size_t)b * K4) << 16) + gy * W_ + gx;
        float v0 = xin[off], v1 = xin[off + HW_];
        float v2 = xin[off + 2 * HW_], v3 = xin[off + 3 * HW_];
        if (mode == 0) {
            v0 = fmaxf(v0, 0.0f); v1 = fmaxf(v1, 0.0f);
            v2 = fmaxf(v2, 0.0f); v3 = fmaxf(v3, 0.0f);
        } else {
            proj4(v0, v1, v2, v3, v0, v1, v2, v3);
        }
        PP_(0, ry, rx) = v0; PP_(1, ry, rx) = v1;
        PP_(2, ry, rx) = v2; PP_(3, ry, rx) = v3;
    }
    __syncthreads();

    // rhs on 16x16, 1 px/thread (reference arithmetic order); also write p
    const float chi = params[4], cap = params[5];
    const int ti = tumor_idx[0];
    int ry = tid >> 4, rx = tid & 15;
    int gy = ty0 + ry, gx = tx0 + rx;
    int row1 = clampi(gy + 1, 0, 255) - ty0;
    int row2 = clampi(gy + 2, 0, 255) - ty0;
    int col1 = clampi(gx + 1, 0, 255) - tx0;
    int col2 = clampi(gx + 2, 0, 255) - tx0;
    float pc[4], px1[4], py1[4], g0x[4], g1x[4], g0y[4], g1y[4];
    float s0x = 0.f, s1x = 0.f, s0y = 0.f, s1y = 0.f;
#pragma unroll
    for (int c = 0; c < 4; ++c) {
        float pcv = PP_(c, ry, rx);
        float a   = PP_(c, ry, col1);
        float bb  = PP_(c, ry, col2);
        float d   = PP_(c, row1, rx);
        float e   = PP_(c, row2, rx);
        pc[c] = pcv; px1[c] = a; py1[c] = d;
        g0x[c] = a - pcv;  g1x[c] = bb - a;
        g0y[c] = d - pcv;  g1y[c] = e - d;
        s0x += g0x[c]; s1x += g1x[c]; s0y += g0y[c]; s1y += g1y[c];
    }
    float km = kmap[((size_t)b << 16) + gy * W_ + gx];
    size_t off = (((size_t)b * K4) << 16) + gy * W_ + gx;
#pragma unroll
    for (int c = 0; c < 4; ++c) {
        float fx0 = -chi * pc[c]  * (s0x - g0x[c]);
        float fx1 = -chi * px1[c] * (s1x - g1x[c]);
        float fy0 = -chi * pc[c]  * (s0y - g0y[c]);
        float fy1 = -chi * py1[c] * (s1y - g1y[c]);
        float cross = (fx0 - fx1) + (fy0 - fy1);
        float react = 0.0f;
        if (c == ti) {
            float pt = fminf(fmaxf(pc[c], 0.0f), 1.0f);
            react = km * pt * (1.0f - pt / cap);
        }
        rhs[off + (size_t)c * HW_]  = pc[c] + DT_ * (cross + react);
        pout[off + (size_t)c * HW_] = pc[c];
    }
}

// ---------------- jacobi8: per-channel, 64x64 tile, 8 sweeps in LDS ----------
#define JROWS 82
#define JSTR 88
#define JTOT (JROWS * JSTR)

__device__ __forceinline__ float4 jac_core(float4 up, float4 dn, float lf, float rt,
                                           float4 ce, float4 rsv,
                                           bool lm, bool rm, float dtD, float wod) {
    float l0 = lm ? ce.x : lf;
    float r3 = rm ? ce.w : rt;
    float4 ov;
    {
        float lap = up.x + dn.x + l0 + ce.y - 4.0f * ce.x;
        float r = rsv.x - (ce.x - dtD * lap);
        ov.x = ce.x + wod * r;
    }
    {
        float lap = up.y + dn.y + ce.x + ce.z - 4.0f * ce.y;
        float r = rsv.y - (ce.y - dtD * lap);
        ov.y = ce.y + wod * r;
    }
    {
        float lap = up.z + dn.z + ce.y + ce.w - 4.0f * ce.z;
        float r = rsv.z - (ce.z - dtD * lap);
        ov.z = ce.z + wod * r;
    }
    {
        float lap = up.w + dn.w + ce.z + r3 - 4.0f * ce.w;
        float r = rsv.w - (ce.w - dtD * lap);
        ov.w = ce.w + wod * r;
    }
    return ov;
}

__global__ __launch_bounds__(1024, 8) void jacobi8_kernel(const float* __restrict__ p,
                                                          const float* __restrict__ rhs,
                                                          const float* __restrict__ params,
                                                          float* __restrict__ xk) {
    __shared__ float jsm[2 * JTOT];
    const int tid = threadIdx.x;
    const int lane = tid & 63;
    const int tx0 = blockIdx.x * 64, ty0 = blockIdx.y * 64;
    const int bc = blockIdx.z;                 // b*4 + c
    const int c  = bc & 3;
    const float* pc_ = p + ((size_t)bc << 16);

    // load region rel [-8..71]^2 (edge-replicate clamp)
    for (int i = tid; i < 80 * 80; i += 1024) {
        int r = i / 80, x = i % 80;
        int gy = clampi(ty0 + r - 8, 0, 255);
        int gx = clampi(tx0 + x - 8, 0, 255);
        jsm[(r + 1) * JSTR + (x + 4)] = pc_[gy * W_ + gx];
    }

    const float dtD = params[6 + c];
    const float wod = params[10 + c];
    const float* rbase = rhs + ((size_t)bc << 16);

    const int ryA = tid / 20, gA = tid % 20;
    const int gyA = ty0 + ryA - 8;
    const int gx0A = tx0 + 4 * gA - 8;
    const int ycA = ryA + 1;
    const int yuA = clampi(gyA - 1, 0, 255) - ty0 + 9;
    const int ydA = clampi(gyA + 1, 0, 255) - ty0 + 9;
    const int ixA = 4 + 4 * gA;
    const bool lmA = (gx0A == 0), rmA = (gx0A == 252);
    const bool lfFixA = (lane == 0 && gA > 0);
    const bool rtFixA = (lane == 63 && gA < 19);

    const bool hasB = (tid < 576);
    const int itB = tid + 1024;
    const int ryB = itB / 20, gB = itB % 20;
    const int gyB = ty0 + ryB - 8;
    const int gx0B = tx0 + 4 * gB - 8;
    const int ycB = ryB + 1;
    const int yuB = clampi(gyB - 1, 0, 255) - ty0 + 9;
    const int ydB = clampi(gyB + 1, 0, 255) - ty0 + 9;
    const int ixB = 4 + 4 * gB;
    const bool lmB = (gx0B == 0), rmB = (gx0B == 252);
    const bool lfFixB = (lane == 0 && gB > 0);
    const bool rtFixB = (lane == 63 && gB < 19);

    float4 rsvA, rsvB;
    {
        const float* rr = rbase + clampi(gyA, 0, 255) * W_;
        if (gx0A >= 0 && gx0A <= 252) {
            rsvA = *(const float4*)&rr[gx0A];
        } else {
            rsvA.x = rr[clampi(gx0A,     0, 255)];
            rsvA.y = rr[clampi(gx0A + 1, 0, 255)];
            rsvA.z = rr[clampi(gx0A + 2, 0, 255)];
            rsvA.w = rr[clampi(gx0A + 3, 0, 255)];
        }
    }
    if (hasB) {
        const float* rr = rbase + clampi(gyB, 0, 255) * W_;
        if (gx0B >= 0 && gx0B <= 252) {
            rsvB = *(const float4*)&rr[gx0B];
        } else {
            rsvB.x = rr[clampi(gx0B,     0, 255)];
            rsvB.y = rr[clampi(gx0B + 1, 0, 255)];
            rsvB.z = rr[clampi(gx0B + 2, 0, 255)];
            rsvB.w = rr[clampi(gx0B + 3, 0, 255)];
        }
    }
    __syncthreads();

    float4 ceA = *(const float4*)&jsm[ycA * JSTR + ixA];
    float4 ceB;
    if (hasB) ceB = *(const float4*)&jsm[ycB * JSTR + ixB];

#pragma unroll
    for (int j = 0; j < 8; ++j) {
        const int rb = j & 1;
        const float* rp = &jsm[rb * JTOT];
        float* wpb = &jsm[(rb ^ 1) * JTOT];

        float lfA = __shfl_up(ceA.w, 1);
        float rtA = __shfl_down(ceA.x, 1);
        if (lfFixA) lfA = rp[ycA * JSTR + ixA - 1];
        if (rtFixA) rtA = rp[ycA * JSTR + ixA + 4];
        float4 upA = *(const float4*)&rp[yuA * JSTR + ixA];
        float4 dnA = *(const float4*)&rp[ydA * JSTR + ixA];
        float4 ovA = jac_core(upA, dnA, lfA, rtA, ceA, rsvA, lmA, rmA, dtD, wod);

        float4 ovB;
        if (hasB) {
            float lfB = __shfl_up(ceB.w, 1);
            float rtB = __shfl_down(ceB.x, 1);
            if (lfFixB) lfB = rp[ycB * JSTR + ixB - 1];
            if (rtFixB) rtB = rp[ycB * JSTR + ixB + 4];
            float4 upB = *(const float4*)&rp[yuB * JSTR + ixB];
            float4 dnB = *(const float4*)&rp[ydB * JSTR + ixB];
            ovB = jac_core(upB, dnB, lfB, rtB, ceB, rsvB, lmB, rmB, dtD, wod);
        }

        if (j < 7) {
            *(float4*)&wpb[ycA * JSTR + ixA] = ovA;
            if (hasB) *(float4*)&wpb[ycB * JSTR + ixB] = ovB;
            __syncthreads();
        }
        ceA = ovA;
        if (hasB) ceB = ovB;
    }

    if (ryA >= 8 && ryA < 72 && gA >= 2 && gA < 18)
        *(float4*)&xk[((size_t)bc << 16) + gyA * W_ + gx0A] = ceA;
    if (hasB && ryB >= 8 && ryB < 72 && gB >= 2 && gB < 18)
        *(float4*)&xk[((size_t)bc << 16) + gyB * W_ + gx0B] = ceB;
}

extern "C" void kernel_launch(void* const* d_in, const int* in_sizes, int n_in,
                              void* d_out, int out_size, void* d_ws, size_t ws_size,
                              hipStream_t stream) {
    const float* p0        = (const float*)d_in[0];
    const float* D_raw     = (const float*)d_in[1];
    const float* chi_raw   = (const float*)d_in[2];
    const float* cap_logit = (const float*)d_in[4];
    const float* w1        = (const float*)d_in[5];
    const float* b1        = (const float*)d_in[6];
    const float* w2        = (const float*)d_in[7];
    const float* b2        = (const float*)d_in[8];
    const float* w3        = (const float*)d_in[9];
    const float* b3        = (const float*)d_in[10];
    const int*   tumor_idx = (const int*)d_in[11];

    char* ws = (char*)d_ws;
    float* params = (float*)(ws + 0);
    float* w1t    = (float*)(ws + 1024);
    float* w2t    = (float*)(ws + 4096);
    float* kmap   = (float*)(ws + 65536);                 // 2 MB
    float* p      = (float*)(ws + 4  * 1024 * 1024);      // 8 MB
    float* rhs    = (float*)(ws + 12 * 1024 * 1024);      // 8 MB
    float* xk     = (float*)d_out;                        // d_out doubles as xk scratch

    setup_kernel<<<1, 256, 0, stream>>>(D_raw, chi_raw, cap_logit, w1, w2,
                                        params, w1t, w2t);
    dim3 cgrid(16, 16, B_);
    cnn_kernel<<<cgrid, 512, 0, stream>>>(p0, w1t, b1, w2t, b2, w3, b3, kmap);

    dim3 pgrid(16, 16, B_);
    dim3 jgrid(4, 4, B_ * K4);
    for (int s = 0; s < STEPS_; ++s) {
        const float* xin = (s == 0) ? p0 : xk;
        proj_rhs_kernel<<<pgrid, 256, 0, stream>>>(xin, kmap, params, tumor_idx,
                                                   p, rhs, s == 0 ? 0 : 1);
        jacobi8_kernel<<<jgrid, 1024, 0, stream>>>(p, rhs, params, xk);
    }
    // final projection, in-place on d_out
    proj_rhs_kernel<<<pgrid, 256, 0, stream>>>(xk, kmap, params, tumor_idx,
                                               xk, rhs, 2);
}